// Round 13
// baseline (252.766 us; speedup 1.0000x reference)
//
#include <hip/hip_runtime.h>
#include <hip/hip_bf16.h>
#include <math.h>

#define NN 100000
#define NE 1600000
#define NG 512
#define NPB 128                        // nodes per bucket
#define NBUCK ((NN + NPB - 1) / NPB)   // 782
#define BCAP 3072                      // record capacity per bucket (mean 2048)
#define PBLOCKS 256
#define GBLKS ((NN + 1 + 127) / 128)   // gemm1 row-blocks, 128 rows each (covers sentinel row NN)

__device__ __forceinline__ float b2f(ushort u){ return __uint_as_float(((unsigned int)u)<<16); }
__device__ __forceinline__ ushort f2b(float f){
    __hip_bfloat16 h = __float2bfloat16(f);      // round-to-nearest
    return *(ushort*)&h;
}
__device__ __forceinline__ float blo(unsigned int u){ return __uint_as_float(u<<16); }
__device__ __forceinline__ float bhi(unsigned int u){ return __uint_as_float(u & 0xffff0000u); }
__device__ __forceinline__ void acc4(float* a, uint2 u){
    a[0] += blo(u.x); a[1] += bhi(u.x); a[2] += blo(u.y); a[3] += bhi(u.y);
}
__device__ __forceinline__ void acc8(float* a, uint4 u){
    a[0] += blo(u.x); a[1] += bhi(u.x); a[2] += blo(u.y); a[3] += bhi(u.y);
    a[4] += blo(u.z); a[5] += bhi(u.z); a[6] += blo(u.w); a[7] += bhi(u.w);
}

// ---------------- merged: interleaved edge-partition / gemm1 blocks (512 threads, overlaid LDS) ----------------
// part (256 blocks, blockIdx&3==0 in first 1024): record=(dst&127)<<17|src -> per-bucket lists
// gemm1 (782 blocks): y1u[r] = bf16( x[r] @ W1 )  (dinv scale deferred to bucket_csr tail)
__global__ __launch_bounds__(512) void merged_kernel(const int* __restrict__ src, const int* __restrict__ dst,
                                                     int* __restrict__ bucket_cnt, int* __restrict__ recs, int e,
                                                     const float* __restrict__ x, const float* __restrict__ W1,
                                                     ushort* __restrict__ y1){
    __shared__ float sW[128*32];        // 16KB; part branch overlays hist/base_ in here
    int tid = threadIdx.x;
    bool is_part = (blockIdx.x < 4*PBLOCKS) && ((blockIdx.x & 3) == 0);
    if(is_part){
        // ---- partition branch ----
        int* hist  = (int*)sW;
        int* base_ = hist + NBUCK;
        int pb = blockIdx.x >> 2;
        for(int b=tid; b<NBUCK; b+=512) hist[b]=0;
        __syncthreads();
        int per = (e + PBLOCKS - 1) / PBLOCKS;
        per = (per + 3) & ~3;
        int lo = pb * per;
        int hi = lo + per; if(hi > e) hi = e;
        if(lo >= hi) return;
        const int4* __restrict__ dst4 = (const int4*)dst;
        const int4* __restrict__ src4 = (const int4*)src;
        for(int i=lo/4+tid; i<hi/4; i+=512){
            int4 d = dst4[i];
            atomicAdd(&hist[d.x>>7], 1);
            atomicAdd(&hist[d.y>>7], 1);
            atomicAdd(&hist[d.z>>7], 1);
            atomicAdd(&hist[d.w>>7], 1);
        }
        __syncthreads();
        for(int b=tid; b<NBUCK; b+=512){
            int h = hist[b];
            base_[b] = h ? atomicAdd(&bucket_cnt[b], h) : 0;
            hist[b] = 0;
        }
        __syncthreads();
        for(int i=lo/4+tid; i<hi/4; i+=512){
            int4 d = dst4[i];
            int4 s = src4[i];
            int b0=d.x>>7, b1=d.y>>7, b2=d.z>>7, b3=d.w>>7;
            int p0 = base_[b0] + atomicAdd(&hist[b0],1);
            int p1 = base_[b1] + atomicAdd(&hist[b1],1);
            int p2 = base_[b2] + atomicAdd(&hist[b2],1);
            int p3 = base_[b3] + atomicAdd(&hist[b3],1);
            if(p0 < BCAP) recs[(size_t)b0*BCAP + p0] = ((d.x & 127) << 17) | s.x;
            if(p1 < BCAP) recs[(size_t)b1*BCAP + p1] = ((d.y & 127) << 17) | s.y;
            if(p2 < BCAP) recs[(size_t)b2*BCAP + p2] = ((d.z & 127) << 17) | s.z;
            if(p3 < BCAP) recs[(size_t)b3*BCAP + p3] = ((d.w & 127) << 17) | s.w;
        }
    } else {
        // ---- gemm1 branch (K=128 -> 32 cols, 512 threads, 128 rows/block, 2 rows/thread) ----
        int gb = (blockIdx.x < 4*PBLOCKS) ? (blockIdx.x - (blockIdx.x>>2) - 1)
                                          : (blockIdx.x - PBLOCKS);
        ((float4*)sW)[tid]     = ((const float4*)W1)[tid];
        ((float4*)sW)[tid+512] = ((const float4*)W1)[tid+512];
        __syncthreads();
        int cg = tid & 7;          // col group of 4
        int rt = tid >> 3;         // 0..63
        int base = gb*128 + rt*2;
        int r0 = base;   if(r0 > NN-1) r0 = NN-1;
        int r1 = base+1; if(r1 > NN-1) r1 = NN-1;
        const float* __restrict__ xp0 = x + (size_t)r0*128;
        const float* __restrict__ xp1 = x + (size_t)r1*128;
        float acc0[4] = {0.f,0.f,0.f,0.f};
        float acc1[4] = {0.f,0.f,0.f,0.f};
        for(int k4=0;k4<32;k4++){
            float4 w0 = *(const float4*)&sW[(k4*4+0)*32 + cg*4];
            float4 w1 = *(const float4*)&sW[(k4*4+1)*32 + cg*4];
            float4 w2 = *(const float4*)&sW[(k4*4+2)*32 + cg*4];
            float4 w3 = *(const float4*)&sW[(k4*4+3)*32 + cg*4];
            float4 xa = ((const float4*)xp0)[k4];
            float4 xb = ((const float4*)xp1)[k4];
            acc0[0] += xa.x*w0.x + xa.y*w1.x + xa.z*w2.x + xa.w*w3.x;
            acc0[1] += xa.x*w0.y + xa.y*w1.y + xa.z*w2.y + xa.w*w3.y;
            acc0[2] += xa.x*w0.z + xa.y*w1.z + xa.z*w2.z + xa.w*w3.z;
            acc0[3] += xa.x*w0.w + xa.y*w1.w + xa.z*w2.w + xa.w*w3.w;
            acc1[0] += xb.x*w0.x + xb.y*w1.x + xb.z*w2.x + xb.w*w3.x;
            acc1[1] += xb.x*w0.y + xb.y*w1.y + xb.z*w2.y + xb.w*w3.y;
            acc1[2] += xb.x*w0.z + xb.y*w1.z + xb.z*w2.z + xb.w*w3.z;
            acc1[3] += xb.x*w0.w + xb.y*w1.w + xb.z*w2.w + xb.w*w3.w;
        }
        #pragma unroll
        for(int j=0;j<2;j++){
            int r = base+j;
            if(r <= NN){
                float* a = j ? acc1 : acc0;
                ushort4 u;
                if(r == NN){ u = make_ushort4(0,0,0,0); }       // sentinel zero row
                else u = make_ushort4(f2b(a[0]), f2b(a[1]), f2b(a[2]), f2b(a[3]));
                *(ushort4*)&y1[(size_t)r*32 + cg*4] = u;
            }
        }
    }
}

// ---------------- bucket -> node CSR (slice-sorted, sentinel-padded rows) + dinv + y1 scale ----------------
__global__ __launch_bounds__(1024) void bucket_csr_kernel(const int* __restrict__ recs, const int* __restrict__ bucket_cnt,
                                                          int* __restrict__ csr, int* __restrict__ row_start,
                                                          int* __restrict__ row_end, float* __restrict__ dinv,
                                                          ushort* __restrict__ y1, int n){
    __shared__ int sr[BCAP];     // staged records
    __shared__ int h2[NPB*8];    // per-(node,slice) counts, then scatter cursors
    __shared__ int pc[NPB];      // prefix of padded totals
    __shared__ int hh[NPB];      // per-node totals
    __shared__ float sdv[NPB];   // dinv for the scale tail
    int b = blockIdx.x, tid = threadIdx.x;
    int cnt = bucket_cnt[b]; if(cnt > BCAP) cnt = BCAP;
    for(int i=tid; i<cnt; i+=1024) sr[i] = recs[(size_t)b*BCAP + i];
    h2[tid] = 0;                 // 1024 == NPB*8
    __syncthreads();
    for(int i=tid; i<cnt; i+=1024){
        int rec = sr[i];
        atomicAdd(&h2[((rec>>17)<<3) | ((rec & 131071)>>14)], 1);
    }
    __syncthreads();
    if(tid < NPB){
        int s = 0;
        #pragma unroll
        for(int k=0;k<8;k++) s += h2[tid*8+k];
        hh[tid] = s;
        pc[tid] = (s+3)&~3;      // pad rows to 4 entries (16B)
    }
    __syncthreads();
    for(int off=1; off<NPB; off<<=1){
        int t = (tid>=off && tid<NPB) ? pc[tid-off] : 0;
        __syncthreads();
        if(tid<NPB) pc[tid] += t;
        __syncthreads();
    }
    if(tid < NPB){
        int h = hh[tid];
        int hp = (h+3)&~3;
        int excl = pc[tid] - hp;
        int run = excl;
        #pragma unroll
        for(int k=0;k<8;k++){ int c = h2[tid*8+k]; h2[tid*8+k] = run; run += c; }
        int node = b*NPB + tid;
        if(node < n){
            row_start[node] = b*BCAP + excl;
            row_end[node]   = b*BCAP + excl + hp;         // padded end -> pure-quad walk
            float dv = rsqrtf((float)(h + 1));            // +1 self-loop
            dinv[node] = dv;
            sdv[tid] = dv;
            for(int k=h; k<hp; k++) csr[(size_t)b*BCAP + excl + k] = NN;   // sentinel pads
        }
    }
    __syncthreads();
    for(int i=tid; i<cnt; i+=1024){
        int rec = sr[i];
        int s = rec & 131071;
        int p = atomicAdd(&h2[((rec>>17)<<3) | (s>>14)], 1);
        csr[(size_t)b*BCAP + p] = s;
    }
    // scale this bucket's y1 rows by dinv (deferred from gemm1): 128 rows x 4 uint4
    if(tid < 512){
        int nl = tid >> 2;
        int node = b*NPB + nl;
        if(node < n){
            float dv = sdv[nl];
            uint4* yp = (uint4*)y1;
            uint4 v = yp[(size_t)node*4 + (tid&3)];
            float t0=blo(v.x)*dv, t1=bhi(v.x)*dv, t2=blo(v.y)*dv, t3=bhi(v.y)*dv;
            float t4=blo(v.z)*dv, t5=bhi(v.z)*dv, t6=blo(v.w)*dv, t7=bhi(v.w)*dv;
            uint4 o;
            o.x = ((unsigned int)f2b(t1)<<16) | (unsigned int)f2b(t0);
            o.y = ((unsigned int)f2b(t3)<<16) | (unsigned int)f2b(t2);
            o.z = ((unsigned int)f2b(t5)<<16) | (unsigned int)f2b(t4);
            o.w = ((unsigned int)f2b(t7)<<16) | (unsigned int)f2b(t6);
            yp[(size_t)node*4 + (tid&3)] = o;
        }
    }
}

// ---------------- prop layer 1: F=32, uint4 (8 bf16/lane, L=4), pipelined pure-quad walk ----------------
__global__ __launch_bounds__(256) void prop1_kernel(const ushort* __restrict__ xin, ushort* __restrict__ xout,
                                                    const int* __restrict__ csr, const int* __restrict__ row_start,
                                                    const int* __restrict__ row_end, const float* __restrict__ dinv,
                                                    const float* __restrict__ bias){
    int gt  = blockIdx.x*256 + threadIdx.x;
    int node = gt >> 2;
    int f4   = gt & 3;
    if(node > NN) return;
    if(node == NN){ ((uint4*)xout)[(size_t)NN*4 + f4] = make_uint4(0,0,0,0); return; }
    float di = dinv[node];
    const uint4* __restrict__ xw = ((const uint4*)xin) + f4;
    float a[8] = {0.f,0.f,0.f,0.f,0.f,0.f,0.f,0.f};
    float b[8] = {0.f,0.f,0.f,0.f,0.f,0.f,0.f,0.f};
    acc8(a, xw[(size_t)node*4]);
    int e  = row_start[node];
    const int* __restrict__ cb = csr + e;
    int nq = (row_end[node] - e) >> 2;
    if(nq >= 2){
        int4 c0 = *(const int4*)(cb);
        int4 c1 = *(const int4*)(cb+4);
        int q = 2;
        for(; q+1 < nq; q += 2){
            int4 n0 = *(const int4*)(cb+4*q);
            int4 n1 = *(const int4*)(cb+4*q+4);
            uint4 u0 = xw[(size_t)c0.x*4];
            uint4 u1 = xw[(size_t)c0.y*4];
            uint4 u2 = xw[(size_t)c0.z*4];
            uint4 u3 = xw[(size_t)c0.w*4];
            uint4 u4 = xw[(size_t)c1.x*4];
            uint4 u5 = xw[(size_t)c1.y*4];
            uint4 u6 = xw[(size_t)c1.z*4];
            uint4 u7 = xw[(size_t)c1.w*4];
            acc8(a,u0); acc8(b,u1); acc8(a,u2); acc8(b,u3);
            acc8(a,u4); acc8(b,u5); acc8(a,u6); acc8(b,u7);
            c0 = n0; c1 = n1;
        }
        {
            uint4 u0 = xw[(size_t)c0.x*4];
            uint4 u1 = xw[(size_t)c0.y*4];
            uint4 u2 = xw[(size_t)c0.z*4];
            uint4 u3 = xw[(size_t)c0.w*4];
            uint4 u4 = xw[(size_t)c1.x*4];
            uint4 u5 = xw[(size_t)c1.y*4];
            uint4 u6 = xw[(size_t)c1.z*4];
            uint4 u7 = xw[(size_t)c1.w*4];
            acc8(a,u0); acc8(b,u1); acc8(a,u2); acc8(b,u3);
            acc8(a,u4); acc8(b,u5); acc8(a,u6); acc8(b,u7);
        }
        if(q < nq){
            int4 c = *(const int4*)(cb+4*q);
            uint4 u0 = xw[(size_t)c.x*4];
            uint4 u1 = xw[(size_t)c.y*4];
            uint4 u2 = xw[(size_t)c.z*4];
            uint4 u3 = xw[(size_t)c.w*4];
            acc8(a,u0); acc8(b,u1); acc8(a,u2); acc8(b,u3);
        }
    } else if(nq == 1){
        int4 c = *(const int4*)(cb);
        uint4 u0 = xw[(size_t)c.x*4];
        uint4 u1 = xw[(size_t)c.y*4];
        uint4 u2 = xw[(size_t)c.z*4];
        uint4 u3 = xw[(size_t)c.w*4];
        acc8(a,u0); acc8(b,u1); acc8(a,u2); acc8(b,u3);
    }
    float r[8];
    #pragma unroll
    for(int j=0;j<8;j++){
        r[j] = di*(a[j]+b[j]) + bias[8*f4+j];
        r[j] = fmaxf(r[j],0.f) * di;
    }
    uint4 outu;
    outu.x = ((unsigned int)f2b(r[1])<<16) | (unsigned int)f2b(r[0]);
    outu.y = ((unsigned int)f2b(r[3])<<16) | (unsigned int)f2b(r[2]);
    outu.z = ((unsigned int)f2b(r[5])<<16) | (unsigned int)f2b(r[4]);
    outu.w = ((unsigned int)f2b(r[7])<<16) | (unsigned int)f2b(r[6]);
    ((uint4*)xout)[(size_t)node*4 + f4] = outu;
}

// ---------------- fused prop(F=32, uint2 L=8) + GEMM(32->64), pipelined walk ----------------
__global__ __launch_bounds__(256) void prop_gemm_kernel(const ushort* __restrict__ xin, ushort* __restrict__ xout,
                                                        const int* __restrict__ csr, const int* __restrict__ row_start,
                                                        const int* __restrict__ row_end, const float* __restrict__ dinv,
                                                        const float* __restrict__ W2, const float* __restrict__ b2){
    __shared__ float4 sW2v[32*16];       // W2[k][c] as rows of 16 float4
    for(int i=threadIdx.x; i<512; i+=256) sW2v[i] = ((const float4*)W2)[i];
    __syncthreads();
    int gt  = blockIdx.x*256 + threadIdx.x;
    int node = gt >> 3;
    int og   = gt & 7;                   // owns input feats 4*og..4*og+3, output cols 8*og..8*og+7
    if(node > NN) return;
    if(node == NN){ ((uint4*)xout)[(size_t)NN*8 + og] = make_uint4(0,0,0,0); return; }
    float di = dinv[node];
    const uint2* __restrict__ xw = ((const uint2*)xin) + og;
    float a[4] = {0.f,0.f,0.f,0.f};
    float b[4] = {0.f,0.f,0.f,0.f};
    acc4(a, xw[(size_t)node*8]);
    int e  = row_start[node];
    const int* __restrict__ cb = csr + e;
    int nq = (row_end[node] - e) >> 2;
    if(nq >= 2){
        int4 c0 = *(const int4*)(cb);
        int4 c1 = *(const int4*)(cb+4);
        int q = 2;
        for(; q+1 < nq; q += 2){
            int4 n0 = *(const int4*)(cb+4*q);
            int4 n1 = *(const int4*)(cb+4*q+4);
            uint2 u0 = xw[(size_t)c0.x*8];
            uint2 u1 = xw[(size_t)c0.y*8];
            uint2 u2 = xw[(size_t)c0.z*8];
            uint2 u3 = xw[(size_t)c0.w*8];
            uint2 u4 = xw[(size_t)c1.x*8];
            uint2 u5 = xw[(size_t)c1.y*8];
            uint2 u6 = xw[(size_t)c1.z*8];
            uint2 u7 = xw[(size_t)c1.w*8];
            acc4(a,u0); acc4(b,u1); acc4(a,u2); acc4(b,u3);
            acc4(a,u4); acc4(b,u5); acc4(a,u6); acc4(b,u7);
            c0 = n0; c1 = n1;
        }
        {
            uint2 u0 = xw[(size_t)c0.x*8];
            uint2 u1 = xw[(size_t)c0.y*8];
            uint2 u2 = xw[(size_t)c0.z*8];
            uint2 u3 = xw[(size_t)c0.w*8];
            uint2 u4 = xw[(size_t)c1.x*8];
            uint2 u5 = xw[(size_t)c1.y*8];
            uint2 u6 = xw[(size_t)c1.z*8];
            uint2 u7 = xw[(size_t)c1.w*8];
            acc4(a,u0); acc4(b,u1); acc4(a,u2); acc4(b,u3);
            acc4(a,u4); acc4(b,u5); acc4(a,u6); acc4(b,u7);
        }
        if(q < nq){
            int4 c = *(const int4*)(cb+4*q);
            uint2 u0 = xw[(size_t)c.x*8];
            uint2 u1 = xw[(size_t)c.y*8];
            uint2 u2 = xw[(size_t)c.z*8];
            uint2 u3 = xw[(size_t)c.w*8];
            acc4(a,u0); acc4(b,u1); acc4(a,u2); acc4(b,u3);
        }
    } else if(nq == 1){
        int4 c = *(const int4*)(cb);
        uint2 u0 = xw[(size_t)c.x*8];
        uint2 u1 = xw[(size_t)c.y*8];
        uint2 u2 = xw[(size_t)c.z*8];
        uint2 u3 = xw[(size_t)c.w*8];
        acc4(a,u0); acc4(b,u1); acc4(a,u2); acc4(b,u3);
    }
    float r[4];
    r[0] = di*(a[0]+b[0]);
    r[1] = di*(a[1]+b[1]);
    r[2] = di*(a[2]+b[2]);
    r[3] = di*(a[3]+b[3]);
    // 32->64 GEMM: broadcast p2[k] across the node's 8 lanes via shfl(width=8)
    float acc[8] = {0.f,0.f,0.f,0.f,0.f,0.f,0.f,0.f};
    #pragma unroll
    for(int k=0;k<32;k++){
        float s = __shfl(r[k&3], k>>2, 8);
        float4 wa = sW2v[k*16 + og*2];
        float4 wb = sW2v[k*16 + og*2 + 1];
        acc[0]+=s*wa.x; acc[1]+=s*wa.y; acc[2]+=s*wa.z; acc[3]+=s*wa.w;
        acc[4]+=s*wb.x; acc[5]+=s*wb.y; acc[6]+=s*wb.z; acc[7]+=s*wb.w;
    }
    float4 ba = *(const float4*)&b2[og*8];
    float4 bb = *(const float4*)&b2[og*8+4];
    float o0 = di*fmaxf(acc[0]+ba.x, 0.f);
    float o1 = di*fmaxf(acc[1]+ba.y, 0.f);
    float o2 = di*fmaxf(acc[2]+ba.z, 0.f);
    float o3 = di*fmaxf(acc[3]+ba.w, 0.f);
    float o4 = di*fmaxf(acc[4]+bb.x, 0.f);
    float o5 = di*fmaxf(acc[5]+bb.y, 0.f);
    float o6 = di*fmaxf(acc[6]+bb.z, 0.f);
    float o7 = di*fmaxf(acc[7]+bb.w, 0.f);
    uint4 u;
    u.x = ((unsigned int)f2b(o1)<<16) | (unsigned int)f2b(o0);
    u.y = ((unsigned int)f2b(o3)<<16) | (unsigned int)f2b(o2);
    u.z = ((unsigned int)f2b(o5)<<16) | (unsigned int)f2b(o4);
    u.w = ((unsigned int)f2b(o7)<<16) | (unsigned int)f2b(o6);
    ((uint4*)xout)[(size_t)node*8 + og] = u;
}

// ---------------- fused prop(F=64, uint4 L=8) + graph pooling, pipelined walk ----------------
__global__ __launch_bounds__(256) void prop_pool_kernel(const ushort* __restrict__ xin,
                                                        const int* __restrict__ csr, const int* __restrict__ row_start,
                                                        const int* __restrict__ row_end, const float* __restrict__ dinv,
                                                        const int* __restrict__ batch, float* __restrict__ pool){
    __shared__ float sp[32*64];
    __shared__ int sg[32];
    int base = blockIdx.x*32;            // grid exactly covers NN (= 3125*32)
    int tid = threadIdx.x;
    int node = base + (tid >> 3);
    int f4 = tid & 7;                    // owns feats 8*f4..8*f4+7
    if(tid < 32) sg[tid] = batch[base+tid];
    float di = dinv[node];
    const uint4* __restrict__ xw = ((const uint4*)xin) + f4;
    float a[8] = {0.f,0.f,0.f,0.f,0.f,0.f,0.f,0.f};
    float b[8] = {0.f,0.f,0.f,0.f,0.f,0.f,0.f,0.f};
    acc8(a, xw[(size_t)node*8]);
    int e  = row_start[node];
    const int* __restrict__ cb = csr + e;
    int nq = (row_end[node] - e) >> 2;
    if(nq >= 2){
        int4 c0 = *(const int4*)(cb);
        int4 c1 = *(const int4*)(cb+4);
        int q = 2;
        for(; q+1 < nq; q += 2){
            int4 n0 = *(const int4*)(cb+4*q);
            int4 n1 = *(const int4*)(cb+4*q+4);
            uint4 u0 = xw[(size_t)c0.x*8];
            uint4 u1 = xw[(size_t)c0.y*8];
            uint4 u2 = xw[(size_t)c0.z*8];
            uint4 u3 = xw[(size_t)c0.w*8];
            uint4 u4 = xw[(size_t)c1.x*8];
            uint4 u5 = xw[(size_t)c1.y*8];
            uint4 u6 = xw[(size_t)c1.z*8];
            uint4 u7 = xw[(size_t)c1.w*8];
            acc8(a,u0); acc8(b,u1); acc8(a,u2); acc8(b,u3);
            acc8(a,u4); acc8(b,u5); acc8(a,u6); acc8(b,u7);
            c0 = n0; c1 = n1;
        }
        {
            uint4 u0 = xw[(size_t)c0.x*8];
            uint4 u1 = xw[(size_t)c0.y*8];
            uint4 u2 = xw[(size_t)c0.z*8];
            uint4 u3 = xw[(size_t)c0.w*8];
            uint4 u4 = xw[(size_t)c1.x*8];
            uint4 u5 = xw[(size_t)c1.y*8];
            uint4 u6 = xw[(size_t)c1.z*8];
            uint4 u7 = xw[(size_t)c1.w*8];
            acc8(a,u0); acc8(b,u1); acc8(a,u2); acc8(b,u3);
            acc8(a,u4); acc8(b,u5); acc8(a,u6); acc8(b,u7);
        }
        if(q < nq){
            int4 c = *(const int4*)(cb+4*q);
            uint4 u0 = xw[(size_t)c.x*8];
            uint4 u1 = xw[(size_t)c.y*8];
            uint4 u2 = xw[(size_t)c.z*8];
            uint4 u3 = xw[(size_t)c.w*8];
            acc8(a,u0); acc8(b,u1); acc8(a,u2); acc8(b,u3);
        }
    } else if(nq == 1){
        int4 c = *(const int4*)(cb);
        uint4 u0 = xw[(size_t)c.x*8];
        uint4 u1 = xw[(size_t)c.y*8];
        uint4 u2 = xw[(size_t)c.z*8];
        uint4 u3 = xw[(size_t)c.w*8];
        acc8(a,u0); acc8(b,u1); acc8(a,u2); acc8(b,u3);
    }
    float4 r0, r1;
    r0.x = di*(a[0]+b[0]); r0.y = di*(a[1]+b[1]); r0.z = di*(a[2]+b[2]); r0.w = di*(a[3]+b[3]);
    r1.x = di*(a[4]+b[4]); r1.y = di*(a[5]+b[5]); r1.z = di*(a[6]+b[6]); r1.w = di*(a[7]+b[7]);
    ((float4*)sp)[tid*2]   = r0;
    ((float4*)sp)[tid*2+1] = r1;
    __syncthreads();
    if(tid < 64){
        int g0 = sg[0], g1 = sg[31];
        for(int g=g0; g<=g1; ++g){
            float s = 0.f;
            #pragma unroll
            for(int nl=0; nl<32; ++nl)
                if(sg[nl]==g) s += sp[nl*64 + tid];
            atomicAdd(&pool[g*64 + tid], s);
        }
    }
}

// ---------------- head: g3 = pool@W3 + cnt*b3; h=relu(g3@Wl1+bl1); logits=h@Wl2+bl2; log_softmax ----------------
__global__ __launch_bounds__(128) void head_kernel(const float* __restrict__ pool, const int* __restrict__ batch, int n,
                                                   const float* __restrict__ W3, const float* __restrict__ b3,
                                                   const float* __restrict__ Wl1, const float* __restrict__ bl1,
                                                   const float* __restrict__ Wl2, const float* __restrict__ bl2,
                                                   float* __restrict__ out){
    __shared__ float sp[64];
    __shared__ float sg3[128];
    __shared__ float sh[64];
    __shared__ float sl[10];
    int g = blockIdx.x, t = threadIdx.x;
    if(t<64) sp[t] = pool[g*64+t];
    __syncthreads();
    int lo=0, hi=n;
    while(lo<hi){ int mid=(lo+hi)>>1; if(batch[mid]<g) lo=mid+1; else hi=mid; }
    int start=lo;
    lo=start; hi=n;
    while(lo<hi){ int mid=(lo+hi)>>1; if(batch[mid]<g+1) lo=mid+1; else hi=mid; }
    float cf = (float)(lo - start);
    float a = cf*b3[t];
    #pragma unroll 8
    for(int k=0;k<64;k++) a += sp[k]*W3[k*128+t];
    sg3[t]=a; __syncthreads();
    if(t<64){
        float h = bl1[t];
        #pragma unroll 8
        for(int k=0;k<128;k++) h += sg3[k]*Wl1[k*64+t];
        sh[t] = fmaxf(h,0.f);
    }
    __syncthreads();
    if(t<10){
        float l = bl2[t];
        for(int k=0;k<64;k++) l += sh[k]*Wl2[k*10+t];
        sl[t]=l;
    }
    __syncthreads();
    if(t<10){
        float m=sl[0];
        for(int k=1;k<10;k++) m=fmaxf(m,sl[k]);
        float s=0.f;
        for(int k=0;k<10;k++) s+=expf(sl[k]-m);
        out[g*10+t] = sl[t]-m-logf(s);
    }
}

extern "C" void kernel_launch(void* const* d_in, const int* in_sizes, int n_in,
                              void* d_out, int out_size, void* d_ws, size_t ws_size,
                              hipStream_t stream){
    const float* x   = (const float*)d_in[0];
    const int*   ei  = (const int*)d_in[1];
    const int* batch = (const int*)d_in[2];
    const float* W1  = (const float*)d_in[3];
    const float* b1  = (const float*)d_in[4];
    const float* W2  = (const float*)d_in[5];
    const float* b2  = (const float*)d_in[6];
    const float* W3  = (const float*)d_in[7];
    const float* b3  = (const float*)d_in[8];
    const float* Wl1 = (const float*)d_in[9];
    const float* bl1 = (const float*)d_in[10];
    const float* Wl2 = (const float*)d_in[11];
    const float* bl2 = (const float*)d_in[12];
    const int n = NN, E = NE;
    const int* src = ei;        // edge_index[0]
    const int* dst = ei + E;    // edge_index[1]

    char* ws = (char*)d_ws;
    size_t off = 0;
    auto alloc = [&](size_t bytes)->char*{
        char* p = ws + off;
        off = (off + bytes + 255) & ~(size_t)255;
        return p;
    };
    // bucket_cnt and pool adjacent -> one memset covers both
    int*    bucket_cnt = (int*)   alloc((size_t)NBUCK*4);
    float*  pool       = (float*) alloc((size_t)NG*64*4); // fp32, atomically accumulated
    size_t  zero_bytes = (size_t)((char*)pool - (char*)bucket_cnt) + (size_t)NG*64*4;
    float*  dinv       = (float*) alloc((size_t)n*4);
    int*    recs       = (int*)   alloc((size_t)NBUCK*BCAP*4);   // 9.6 MB
    int*    csr        = (int*)   alloc((size_t)NBUCK*BCAP*4);   // 9.6 MB
    int*    row_start  = (int*)   alloc((size_t)n*4);
    int*    row_end    = (int*)   alloc((size_t)n*4);
    ushort* y1         = (ushort*)alloc((size_t)(n+1)*32*2);  // bf16, +1 sentinel zero row
    ushort* h1y        = (ushort*)alloc((size_t)(n+1)*32*2);  // bf16, +1 sentinel zero row
    ushort* h2y        = (ushort*)alloc((size_t)(n+1)*64*2);  // bf16, +1 sentinel zero row

    hipMemsetAsync(bucket_cnt, 0, zero_bytes, stream);
    // interleaved part (256 blocks) + unscaled gemm1 (782 blocks), 512 threads each
    merged_kernel<<<PBLOCKS+GBLKS,512,0,stream>>>(src, dst, bucket_cnt, recs, E, x, W1, y1);
    // CSR build (slice-sorted, sentinel-padded) + dinv + deferred y1 scale
    bucket_csr_kernel<<<NBUCK,1024,0,stream>>>(recs, bucket_cnt, csr, row_start, row_end, dinv, y1, n);
    // layer 1 propagate
    prop1_kernel<<<((n+1)*4+255)/256,256,0,stream>>>(y1, h1y, csr, row_start, row_end, dinv, b1);
    // layer 2 fused prop+GEMM
    prop_gemm_kernel<<<((n+1)*8+255)/256,256,0,stream>>>(h1y, h2y, csr, row_start, row_end, dinv, W2, b2);
    // layer 3 fused prop+pooling
    prop_pool_kernel<<<n/32,256,0,stream>>>(h2y, csr, row_start, row_end, dinv, batch, pool);
    // tiny head
    head_kernel<<<NG,128,0,stream>>>(pool, batch, n, W3, b3, Wl1, bl1, Wl2, bl2, (float*)d_out);
}

// Round 14
// 248.342 us; speedup vs baseline: 1.0178x; 1.0178x over previous
//
#include <hip/hip_runtime.h>
#include <hip/hip_bf16.h>
#include <math.h>

#define NN 100000
#define NE 1600000
#define NG 512
#define NPB 128                        // nodes per bucket
#define NBUCK ((NN + NPB - 1) / NPB)   // 782
#define BCAP 3072                      // record capacity per bucket (mean 2048)
#define PBLOCKS 256
#define GBLKS ((NN + 1 + 255) / 256)   // gemm1 row-blocks (covers sentinel row NN)

__device__ __forceinline__ float b2f(ushort u){ return __uint_as_float(((unsigned int)u)<<16); }
__device__ __forceinline__ ushort f2b(float f){
    __hip_bfloat16 h = __float2bfloat16(f);      // round-to-nearest
    return *(ushort*)&h;
}
__device__ __forceinline__ float blo(unsigned int u){ return __uint_as_float(u<<16); }
__device__ __forceinline__ float bhi(unsigned int u){ return __uint_as_float(u & 0xffff0000u); }
__device__ __forceinline__ void acc4(float* a, uint2 u){
    a[0] += blo(u.x); a[1] += bhi(u.x); a[2] += blo(u.y); a[3] += bhi(u.y);
}
__device__ __forceinline__ void acc8(float* a, uint4 u){
    a[0] += blo(u.x); a[1] += bhi(u.x); a[2] += blo(u.y); a[3] += bhi(u.y);
    a[4] += blo(u.z); a[5] += bhi(u.z); a[6] += blo(u.w); a[7] += bhi(u.w);
}

// ---------------- merged: [blocks 0..PBLOCKS) edge partition | [PBLOCKS..) gemm1 (unscaled) ----------------
// part: record = (dst&127)<<17 | src  -> per-bucket lists (block-local write runs)
// gemm1: y1u[r] = bf16( x[r] @ W1 )   (dinv scale deferred to bucket_csr tail)
__global__ __launch_bounds__(1024) void merged_kernel(const int* __restrict__ src, const int* __restrict__ dst,
                                                      int* __restrict__ bucket_cnt, int* __restrict__ recs, int e,
                                                      const float* __restrict__ x, const float* __restrict__ W1,
                                                      ushort* __restrict__ y1){
    __shared__ int hist[NBUCK];
    __shared__ int base_[NBUCK];
    __shared__ float sW[128*32];
    int tid = threadIdx.x;
    if(blockIdx.x < PBLOCKS){
        // ---- partition branch ----
        for(int b=tid; b<NBUCK; b+=1024) hist[b]=0;
        __syncthreads();
        int per = (e + PBLOCKS - 1) / PBLOCKS;
        per = (per + 3) & ~3;
        int lo = blockIdx.x * per;
        int hi = lo + per; if(hi > e) hi = e;
        if(lo >= hi) return;
        const int4* __restrict__ dst4 = (const int4*)dst;
        const int4* __restrict__ src4 = (const int4*)src;
        for(int i=lo/4+tid; i<hi/4; i+=1024){
            int4 d = dst4[i];
            atomicAdd(&hist[d.x>>7], 1);
            atomicAdd(&hist[d.y>>7], 1);
            atomicAdd(&hist[d.z>>7], 1);
            atomicAdd(&hist[d.w>>7], 1);
        }
        __syncthreads();
        for(int b=tid; b<NBUCK; b+=1024){
            int h = hist[b];
            base_[b] = h ? atomicAdd(&bucket_cnt[b], h) : 0;
            hist[b] = 0;
        }
        __syncthreads();
        for(int i=lo/4+tid; i<hi/4; i+=1024){
            int4 d = dst4[i];
            int4 s = src4[i];
            int b0=d.x>>7, b1=d.y>>7, b2=d.z>>7, b3=d.w>>7;
            int p0 = base_[b0] + atomicAdd(&hist[b0],1);
            int p1 = base_[b1] + atomicAdd(&hist[b1],1);
            int p2 = base_[b2] + atomicAdd(&hist[b2],1);
            int p3 = base_[b3] + atomicAdd(&hist[b3],1);
            if(p0 < BCAP) recs[(size_t)b0*BCAP + p0] = ((d.x & 127) << 17) | s.x;
            if(p1 < BCAP) recs[(size_t)b1*BCAP + p1] = ((d.y & 127) << 17) | s.y;
            if(p2 < BCAP) recs[(size_t)b2*BCAP + p2] = ((d.z & 127) << 17) | s.z;
            if(p3 < BCAP) recs[(size_t)b3*BCAP + p3] = ((d.w & 127) << 17) | s.w;
        }
    } else {
        // ---- gemm1 branch (K=128 -> 32 cols, 1024 threads, 2 rows/thread) ----
        int gblk = blockIdx.x - PBLOCKS;
        ((float4*)sW)[tid] = ((const float4*)W1)[tid];   // 1024 float4 == 16KB
        __syncthreads();
        int cg = tid & 7;          // col group of 4
        int rt = tid >> 3;         // 0..127
        int base = gblk*256 + rt*2;
        int r0 = base;   if(r0 > NN-1) r0 = NN-1;
        int r1 = base+1; if(r1 > NN-1) r1 = NN-1;
        const float* __restrict__ xp0 = x + (size_t)r0*128;
        const float* __restrict__ xp1 = x + (size_t)r1*128;
        float acc0[4] = {0.f,0.f,0.f,0.f};
        float acc1[4] = {0.f,0.f,0.f,0.f};
        for(int k4=0;k4<32;k4++){
            float4 w0 = *(const float4*)&sW[(k4*4+0)*32 + cg*4];
            float4 w1 = *(const float4*)&sW[(k4*4+1)*32 + cg*4];
            float4 w2 = *(const float4*)&sW[(k4*4+2)*32 + cg*4];
            float4 w3 = *(const float4*)&sW[(k4*4+3)*32 + cg*4];
            float4 xa = ((const float4*)xp0)[k4];
            float4 xb = ((const float4*)xp1)[k4];
            acc0[0] += xa.x*w0.x + xa.y*w1.x + xa.z*w2.x + xa.w*w3.x;
            acc0[1] += xa.x*w0.y + xa.y*w1.y + xa.z*w2.y + xa.w*w3.y;
            acc0[2] += xa.x*w0.z + xa.y*w1.z + xa.z*w2.z + xa.w*w3.z;
            acc0[3] += xa.x*w0.w + xa.y*w1.w + xa.z*w2.w + xa.w*w3.w;
            acc1[0] += xb.x*w0.x + xb.y*w1.x + xb.z*w2.x + xb.w*w3.x;
            acc1[1] += xb.x*w0.y + xb.y*w1.y + xb.z*w2.y + xb.w*w3.y;
            acc1[2] += xb.x*w0.z + xb.y*w1.z + xb.z*w2.z + xb.w*w3.z;
            acc1[3] += xb.x*w0.w + xb.y*w1.w + xb.z*w2.w + xb.w*w3.w;
        }
        #pragma unroll
        for(int j=0;j<2;j++){
            int r = base+j;
            if(r <= NN){
                float* a = j ? acc1 : acc0;
                ushort4 u;
                if(r == NN){ u = make_ushort4(0,0,0,0); }       // sentinel zero row
                else u = make_ushort4(f2b(a[0]), f2b(a[1]), f2b(a[2]), f2b(a[3]));
                *(ushort4*)&y1[(size_t)r*32 + cg*4] = u;
            }
        }
    }
}

// ---------------- bucket -> node CSR (slice-sorted, sentinel-padded rows) + dinv + y1 scale ----------------
__global__ __launch_bounds__(1024) void bucket_csr_kernel(const int* __restrict__ recs, const int* __restrict__ bucket_cnt,
                                                          int* __restrict__ csr, int* __restrict__ row_start,
                                                          int* __restrict__ row_end, float* __restrict__ dinv,
                                                          ushort* __restrict__ y1, int n){
    __shared__ int sr[BCAP];     // staged records
    __shared__ int h2[NPB*8];    // per-(node,slice) counts, then scatter cursors
    __shared__ int pc[NPB];      // prefix of padded totals
    __shared__ int hh[NPB];      // per-node totals
    __shared__ float sdv[NPB];   // dinv for the scale tail
    int b = blockIdx.x, tid = threadIdx.x;
    int cnt = bucket_cnt[b]; if(cnt > BCAP) cnt = BCAP;
    for(int i=tid; i<cnt; i+=1024) sr[i] = recs[(size_t)b*BCAP + i];
    h2[tid] = 0;                 // 1024 == NPB*8
    __syncthreads();
    for(int i=tid; i<cnt; i+=1024){
        int rec = sr[i];
        atomicAdd(&h2[((rec>>17)<<3) | ((rec & 131071)>>14)], 1);
    }
    __syncthreads();
    if(tid < NPB){
        int s = 0;
        #pragma unroll
        for(int k=0;k<8;k++) s += h2[tid*8+k];
        hh[tid] = s;
        pc[tid] = (s+3)&~3;      // pad rows to 4 entries (16B)
    }
    __syncthreads();
    for(int off=1; off<NPB; off<<=1){
        int t = (tid>=off && tid<NPB) ? pc[tid-off] : 0;
        __syncthreads();
        if(tid<NPB) pc[tid] += t;
        __syncthreads();
    }
    if(tid < NPB){
        int h = hh[tid];
        int hp = (h+3)&~3;
        int excl = pc[tid] - hp;
        int run = excl;
        #pragma unroll
        for(int k=0;k<8;k++){ int c = h2[tid*8+k]; h2[tid*8+k] = run; run += c; }
        int node = b*NPB + tid;
        if(node < n){
            row_start[node] = b*BCAP + excl;
            row_end[node]   = b*BCAP + excl + hp;         // padded end -> pure-quad walk
            float dv = rsqrtf((float)(h + 1));            // +1 self-loop
            dinv[node] = dv;
            sdv[tid] = dv;
            for(int k=h; k<hp; k++) csr[(size_t)b*BCAP + excl + k] = NN;   // sentinel pads
        }
    }
    __syncthreads();
    for(int i=tid; i<cnt; i+=1024){
        int rec = sr[i];
        int s = rec & 131071;
        int p = atomicAdd(&h2[((rec>>17)<<3) | (s>>14)], 1);
        csr[(size_t)b*BCAP + p] = s;
    }
    // scale this bucket's y1 rows by dinv (deferred from gemm1): 128 rows x 4 uint4
    if(tid < 512){
        int nl = tid >> 2;
        int node = b*NPB + nl;
        if(node < n){
            float dv = sdv[nl];
            uint4* yp = (uint4*)y1;
            uint4 v = yp[(size_t)node*4 + (tid&3)];
            float t0=blo(v.x)*dv, t1=bhi(v.x)*dv, t2=blo(v.y)*dv, t3=bhi(v.y)*dv;
            float t4=blo(v.z)*dv, t5=bhi(v.z)*dv, t6=blo(v.w)*dv, t7=bhi(v.w)*dv;
            uint4 o;
            o.x = ((unsigned int)f2b(t1)<<16) | (unsigned int)f2b(t0);
            o.y = ((unsigned int)f2b(t3)<<16) | (unsigned int)f2b(t2);
            o.z = ((unsigned int)f2b(t5)<<16) | (unsigned int)f2b(t4);
            o.w = ((unsigned int)f2b(t7)<<16) | (unsigned int)f2b(t6);
            yp[(size_t)node*4 + (tid&3)] = o;
        }
    }
}

// ---------------- prop layer 1: F=32, uint4 (8 bf16/lane, L=4), pipelined pure-quad walk ----------------
// h1y[i] = bf16( dinv_i * relu( dinv_i*(y1[i] + sum y1[src]) + b1 ) )
__global__ __launch_bounds__(256) void prop1_kernel(const ushort* __restrict__ xin, ushort* __restrict__ xout,
                                                    const int* __restrict__ csr, const int* __restrict__ row_start,
                                                    const int* __restrict__ row_end, const float* __restrict__ dinv,
                                                    const float* __restrict__ bias){
    int gt  = blockIdx.x*256 + threadIdx.x;
    int node = gt >> 2;
    int f4   = gt & 3;
    if(node > NN) return;
    if(node == NN){ ((uint4*)xout)[(size_t)NN*4 + f4] = make_uint4(0,0,0,0); return; }
    float di = dinv[node];
    const uint4* __restrict__ xw = ((const uint4*)xin) + f4;
    float a[8] = {0.f,0.f,0.f,0.f,0.f,0.f,0.f,0.f};
    float b[8] = {0.f,0.f,0.f,0.f,0.f,0.f,0.f,0.f};
    acc8(a, xw[(size_t)node*4]);
    int e  = row_start[node];
    const int* __restrict__ cb = csr + e;
    int nq = (row_end[node] - e) >> 2;
    if(nq >= 2){
        int4 c0 = *(const int4*)(cb);
        int4 c1 = *(const int4*)(cb+4);
        int q = 2;
        for(; q+1 < nq; q += 2){
            int4 n0 = *(const int4*)(cb+4*q);
            int4 n1 = *(const int4*)(cb+4*q+4);
            uint4 u0 = xw[(size_t)c0.x*4];
            uint4 u1 = xw[(size_t)c0.y*4];
            uint4 u2 = xw[(size_t)c0.z*4];
            uint4 u3 = xw[(size_t)c0.w*4];
            uint4 u4 = xw[(size_t)c1.x*4];
            uint4 u5 = xw[(size_t)c1.y*4];
            uint4 u6 = xw[(size_t)c1.z*4];
            uint4 u7 = xw[(size_t)c1.w*4];
            acc8(a,u0); acc8(b,u1); acc8(a,u2); acc8(b,u3);
            acc8(a,u4); acc8(b,u5); acc8(a,u6); acc8(b,u7);
            c0 = n0; c1 = n1;
        }
        {
            uint4 u0 = xw[(size_t)c0.x*4];
            uint4 u1 = xw[(size_t)c0.y*4];
            uint4 u2 = xw[(size_t)c0.z*4];
            uint4 u3 = xw[(size_t)c0.w*4];
            uint4 u4 = xw[(size_t)c1.x*4];
            uint4 u5 = xw[(size_t)c1.y*4];
            uint4 u6 = xw[(size_t)c1.z*4];
            uint4 u7 = xw[(size_t)c1.w*4];
            acc8(a,u0); acc8(b,u1); acc8(a,u2); acc8(b,u3);
            acc8(a,u4); acc8(b,u5); acc8(a,u6); acc8(b,u7);
        }
        if(q < nq){
            int4 c = *(const int4*)(cb+4*q);
            uint4 u0 = xw[(size_t)c.x*4];
            uint4 u1 = xw[(size_t)c.y*4];
            uint4 u2 = xw[(size_t)c.z*4];
            uint4 u3 = xw[(size_t)c.w*4];
            acc8(a,u0); acc8(b,u1); acc8(a,u2); acc8(b,u3);
        }
    } else if(nq == 1){
        int4 c = *(const int4*)(cb);
        uint4 u0 = xw[(size_t)c.x*4];
        uint4 u1 = xw[(size_t)c.y*4];
        uint4 u2 = xw[(size_t)c.z*4];
        uint4 u3 = xw[(size_t)c.w*4];
        acc8(a,u0); acc8(b,u1); acc8(a,u2); acc8(b,u3);
    }
    float r[8];
    #pragma unroll
    for(int j=0;j<8;j++){
        r[j] = di*(a[j]+b[j]) + bias[8*f4+j];
        r[j] = fmaxf(r[j],0.f) * di;
    }
    uint4 outu;
    outu.x = ((unsigned int)f2b(r[1])<<16) | (unsigned int)f2b(r[0]);
    outu.y = ((unsigned int)f2b(r[3])<<16) | (unsigned int)f2b(r[2]);
    outu.z = ((unsigned int)f2b(r[5])<<16) | (unsigned int)f2b(r[4]);
    outu.w = ((unsigned int)f2b(r[7])<<16) | (unsigned int)f2b(r[6]);
    ((uint4*)xout)[(size_t)node*4 + f4] = outu;
}

// ---------------- fused prop(F=32, uint2 L=8) + GEMM(32->64), pipelined walk ----------------
__global__ __launch_bounds__(256) void prop_gemm_kernel(const ushort* __restrict__ xin, ushort* __restrict__ xout,
                                                        const int* __restrict__ csr, const int* __restrict__ row_start,
                                                        const int* __restrict__ row_end, const float* __restrict__ dinv,
                                                        const float* __restrict__ W2, const float* __restrict__ b2){
    __shared__ float4 sW2v[32*16];       // W2[k][c] as rows of 16 float4
    for(int i=threadIdx.x; i<512; i+=256) sW2v[i] = ((const float4*)W2)[i];
    __syncthreads();
    int gt  = blockIdx.x*256 + threadIdx.x;
    int node = gt >> 3;
    int og   = gt & 7;                   // owns input feats 4*og..4*og+3, output cols 8*og..8*og+7
    if(node > NN) return;
    if(node == NN){ ((uint4*)xout)[(size_t)NN*8 + og] = make_uint4(0,0,0,0); return; }
    float di = dinv[node];
    const uint2* __restrict__ xw = ((const uint2*)xin) + og;
    float a[4] = {0.f,0.f,0.f,0.f};
    float b[4] = {0.f,0.f,0.f,0.f};
    acc4(a, xw[(size_t)node*8]);
    int e  = row_start[node];
    const int* __restrict__ cb = csr + e;
    int nq = (row_end[node] - e) >> 2;
    if(nq >= 2){
        int4 c0 = *(const int4*)(cb);
        int4 c1 = *(const int4*)(cb+4);
        int q = 2;
        for(; q+1 < nq; q += 2){
            int4 n0 = *(const int4*)(cb+4*q);
            int4 n1 = *(const int4*)(cb+4*q+4);
            uint2 u0 = xw[(size_t)c0.x*8];
            uint2 u1 = xw[(size_t)c0.y*8];
            uint2 u2 = xw[(size_t)c0.z*8];
            uint2 u3 = xw[(size_t)c0.w*8];
            uint2 u4 = xw[(size_t)c1.x*8];
            uint2 u5 = xw[(size_t)c1.y*8];
            uint2 u6 = xw[(size_t)c1.z*8];
            uint2 u7 = xw[(size_t)c1.w*8];
            acc4(a,u0); acc4(b,u1); acc4(a,u2); acc4(b,u3);
            acc4(a,u4); acc4(b,u5); acc4(a,u6); acc4(b,u7);
            c0 = n0; c1 = n1;
        }
        {
            uint2 u0 = xw[(size_t)c0.x*8];
            uint2 u1 = xw[(size_t)c0.y*8];
            uint2 u2 = xw[(size_t)c0.z*8];
            uint2 u3 = xw[(size_t)c0.w*8];
            uint2 u4 = xw[(size_t)c1.x*8];
            uint2 u5 = xw[(size_t)c1.y*8];
            uint2 u6 = xw[(size_t)c1.z*8];
            uint2 u7 = xw[(size_t)c1.w*8];
            acc4(a,u0); acc4(b,u1); acc4(a,u2); acc4(b,u3);
            acc4(a,u4); acc4(b,u5); acc4(a,u6); acc4(b,u7);
        }
        if(q < nq){
            int4 c = *(const int4*)(cb+4*q);
            uint2 u0 = xw[(size_t)c.x*8];
            uint2 u1 = xw[(size_t)c.y*8];
            uint2 u2 = xw[(size_t)c.z*8];
            uint2 u3 = xw[(size_t)c.w*8];
            acc4(a,u0); acc4(b,u1); acc4(a,u2); acc4(b,u3);
        }
    } else if(nq == 1){
        int4 c = *(const int4*)(cb);
        uint2 u0 = xw[(size_t)c.x*8];
        uint2 u1 = xw[(size_t)c.y*8];
        uint2 u2 = xw[(size_t)c.z*8];
        uint2 u3 = xw[(size_t)c.w*8];
        acc4(a,u0); acc4(b,u1); acc4(a,u2); acc4(b,u3);
    }
    float r[4];
    r[0] = di*(a[0]+b[0]);
    r[1] = di*(a[1]+b[1]);
    r[2] = di*(a[2]+b[2]);
    r[3] = di*(a[3]+b[3]);
    // 32->64 GEMM: broadcast p2[k] across the node's 8 lanes via shfl(width=8)
    float acc[8] = {0.f,0.f,0.f,0.f,0.f,0.f,0.f,0.f};
    #pragma unroll
    for(int k=0;k<32;k++){
        float s = __shfl(r[k&3], k>>2, 8);
        float4 wa = sW2v[k*16 + og*2];
        float4 wb = sW2v[k*16 + og*2 + 1];
        acc[0]+=s*wa.x; acc[1]+=s*wa.y; acc[2]+=s*wa.z; acc[3]+=s*wa.w;
        acc[4]+=s*wb.x; acc[5]+=s*wb.y; acc[6]+=s*wb.z; acc[7]+=s*wb.w;
    }
    float4 ba = *(const float4*)&b2[og*8];
    float4 bb = *(const float4*)&b2[og*8+4];
    float o0 = di*fmaxf(acc[0]+ba.x, 0.f);
    float o1 = di*fmaxf(acc[1]+ba.y, 0.f);
    float o2 = di*fmaxf(acc[2]+ba.z, 0.f);
    float o3 = di*fmaxf(acc[3]+ba.w, 0.f);
    float o4 = di*fmaxf(acc[4]+bb.x, 0.f);
    float o5 = di*fmaxf(acc[5]+bb.y, 0.f);
    float o6 = di*fmaxf(acc[6]+bb.z, 0.f);
    float o7 = di*fmaxf(acc[7]+bb.w, 0.f);
    uint4 u;
    u.x = ((unsigned int)f2b(o1)<<16) | (unsigned int)f2b(o0);
    u.y = ((unsigned int)f2b(o3)<<16) | (unsigned int)f2b(o2);
    u.z = ((unsigned int)f2b(o5)<<16) | (unsigned int)f2b(o4);
    u.w = ((unsigned int)f2b(o7)<<16) | (unsigned int)f2b(o6);
    ((uint4*)xout)[(size_t)node*8 + og] = u;
}

// ---------------- fused prop(F=64, uint4 L=8) + graph pooling, pipelined walk ----------------
__global__ __launch_bounds__(256) void prop_pool_kernel(const ushort* __restrict__ xin,
                                                        const int* __restrict__ csr, const int* __restrict__ row_start,
                                                        const int* __restrict__ row_end, const float* __restrict__ dinv,
                                                        const int* __restrict__ batch, float* __restrict__ pool){
    __shared__ float sp[32*64];
    __shared__ int sg[32];
    int base = blockIdx.x*32;            // grid exactly covers NN (= 3125*32)
    int tid = threadIdx.x;
    int node = base + (tid >> 3);
    int f4 = tid & 7;                    // owns feats 8*f4..8*f4+7
    if(tid < 32) sg[tid] = batch[base+tid];
    float di = dinv[node];
    const uint4* __restrict__ xw = ((const uint4*)xin) + f4;
    float a[8] = {0.f,0.f,0.f,0.f,0.f,0.f,0.f,0.f};
    float b[8] = {0.f,0.f,0.f,0.f,0.f,0.f,0.f,0.f};
    acc8(a, xw[(size_t)node*8]);
    int e  = row_start[node];
    const int* __restrict__ cb = csr + e;
    int nq = (row_end[node] - e) >> 2;
    if(nq >= 2){
        int4 c0 = *(const int4*)(cb);
        int4 c1 = *(const int4*)(cb+4);
        int q = 2;
        for(; q+1 < nq; q += 2){
            int4 n0 = *(const int4*)(cb+4*q);
            int4 n1 = *(const int4*)(cb+4*q+4);
            uint4 u0 = xw[(size_t)c0.x*8];
            uint4 u1 = xw[(size_t)c0.y*8];
            uint4 u2 = xw[(size_t)c0.z*8];
            uint4 u3 = xw[(size_t)c0.w*8];
            uint4 u4 = xw[(size_t)c1.x*8];
            uint4 u5 = xw[(size_t)c1.y*8];
            uint4 u6 = xw[(size_t)c1.z*8];
            uint4 u7 = xw[(size_t)c1.w*8];
            acc8(a,u0); acc8(b,u1); acc8(a,u2); acc8(b,u3);
            acc8(a,u4); acc8(b,u5); acc8(a,u6); acc8(b,u7);
            c0 = n0; c1 = n1;
        }
        {
            uint4 u0 = xw[(size_t)c0.x*8];
            uint4 u1 = xw[(size_t)c0.y*8];
            uint4 u2 = xw[(size_t)c0.z*8];
            uint4 u3 = xw[(size_t)c0.w*8];
            uint4 u4 = xw[(size_t)c1.x*8];
            uint4 u5 = xw[(size_t)c1.y*8];
            uint4 u6 = xw[(size_t)c1.z*8];
            uint4 u7 = xw[(size_t)c1.w*8];
            acc8(a,u0); acc8(b,u1); acc8(a,u2); acc8(b,u3);
            acc8(a,u4); acc8(b,u5); acc8(a,u6); acc8(b,u7);
        }
        if(q < nq){
            int4 c = *(const int4*)(cb+4*q);
            uint4 u0 = xw[(size_t)c.x*8];
            uint4 u1 = xw[(size_t)c.y*8];
            uint4 u2 = xw[(size_t)c.z*8];
            uint4 u3 = xw[(size_t)c.w*8];
            acc8(a,u0); acc8(b,u1); acc8(a,u2); acc8(b,u3);
        }
    } else if(nq == 1){
        int4 c = *(const int4*)(cb);
        uint4 u0 = xw[(size_t)c.x*8];
        uint4 u1 = xw[(size_t)c.y*8];
        uint4 u2 = xw[(size_t)c.z*8];
        uint4 u3 = xw[(size_t)c.w*8];
        acc8(a,u0); acc8(b,u1); acc8(a,u2); acc8(b,u3);
    }
    float4 r0, r1;
    r0.x = di*(a[0]+b[0]); r0.y = di*(a[1]+b[1]); r0.z = di*(a[2]+b[2]); r0.w = di*(a[3]+b[3]);
    r1.x = di*(a[4]+b[4]); r1.y = di*(a[5]+b[5]); r1.z = di*(a[6]+b[6]); r1.w = di*(a[7]+b[7]);
    ((float4*)sp)[tid*2]   = r0;
    ((float4*)sp)[tid*2+1] = r1;
    __syncthreads();
    if(tid < 64){
        int g0 = sg[0], g1 = sg[31];
        for(int g=g0; g<=g1; ++g){
            float s = 0.f;
            #pragma unroll
            for(int nl=0; nl<32; ++nl)
                if(sg[nl]==g) s += sp[nl*64 + tid];
            atomicAdd(&pool[g*64 + tid], s);
        }
    }
}

// ---------------- head: g3 = pool@W3 + cnt*b3; h=relu(g3@Wl1+bl1); logits=h@Wl2+bl2; log_softmax ----------------
__global__ __launch_bounds__(128) void head_kernel(const float* __restrict__ pool, const int* __restrict__ batch, int n,
                                                   const float* __restrict__ W3, const float* __restrict__ b3,
                                                   const float* __restrict__ Wl1, const float* __restrict__ bl1,
                                                   const float* __restrict__ Wl2, const float* __restrict__ bl2,
                                                   float* __restrict__ out){
    __shared__ float sp[64];
    __shared__ float sg3[128];
    __shared__ float sh[64];
    __shared__ float sl[10];
    int g = blockIdx.x, t = threadIdx.x;
    if(t<64) sp[t] = pool[g*64+t];
    __syncthreads();
    int lo=0, hi=n;
    while(lo<hi){ int mid=(lo+hi)>>1; if(batch[mid]<g) lo=mid+1; else hi=mid; }
    int start=lo;
    lo=start; hi=n;
    while(lo<hi){ int mid=(lo+hi)>>1; if(batch[mid]<g+1) lo=mid+1; else hi=mid; }
    float cf = (float)(lo - start);
    float a = cf*b3[t];
    #pragma unroll 8
    for(int k=0;k<64;k++) a += sp[k]*W3[k*128+t];
    sg3[t]=a; __syncthreads();
    if(t<64){
        float h = bl1[t];
        #pragma unroll 8
        for(int k=0;k<128;k++) h += sg3[k]*Wl1[k*64+t];
        sh[t] = fmaxf(h,0.f);
    }
    __syncthreads();
    if(t<10){
        float l = bl2[t];
        for(int k=0;k<64;k++) l += sh[k]*Wl2[k*10+t];
        sl[t]=l;
    }
    __syncthreads();
    if(t<10){
        float m=sl[0];
        for(int k=1;k<10;k++) m=fmaxf(m,sl[k]);
        float s=0.f;
        for(int k=0;k<10;k++) s+=expf(sl[k]-m);
        out[g*10+t] = sl[t]-m-logf(s);
    }
}

extern "C" void kernel_launch(void* const* d_in, const int* in_sizes, int n_in,
                              void* d_out, int out_size, void* d_ws, size_t ws_size,
                              hipStream_t stream){
    const float* x   = (const float*)d_in[0];
    const int*   ei  = (const int*)d_in[1];
    const int* batch = (const int*)d_in[2];
    const float* W1  = (const float*)d_in[3];
    const float* b1  = (const float*)d_in[4];
    const float* W2  = (const float*)d_in[5];
    const float* b2  = (const float*)d_in[6];
    const float* W3  = (const float*)d_in[7];
    const float* b3  = (const float*)d_in[8];
    const float* Wl1 = (const float*)d_in[9];
    const float* bl1 = (const float*)d_in[10];
    const float* Wl2 = (const float*)d_in[11];
    const float* bl2 = (const float*)d_in[12];
    const int n = NN, E = NE;
    const int* src = ei;        // edge_index[0]
    const int* dst = ei + E;    // edge_index[1]

    char* ws = (char*)d_ws;
    size_t off = 0;
    auto alloc = [&](size_t bytes)->char*{
        char* p = ws + off;
        off = (off + bytes + 255) & ~(size_t)255;
        return p;
    };
    // bucket_cnt and pool adjacent -> one memset covers both
    int*    bucket_cnt = (int*)   alloc((size_t)NBUCK*4);
    float*  pool       = (float*) alloc((size_t)NG*64*4); // fp32, atomically accumulated
    size_t  zero_bytes = (size_t)((char*)pool - (char*)bucket_cnt) + (size_t)NG*64*4;
    float*  dinv       = (float*) alloc((size_t)n*4);
    int*    recs       = (int*)   alloc((size_t)NBUCK*BCAP*4);   // 9.6 MB
    int*    csr        = (int*)   alloc((size_t)NBUCK*BCAP*4);   // 9.6 MB
    int*    row_start  = (int*)   alloc((size_t)n*4);
    int*    row_end    = (int*)   alloc((size_t)n*4);
    ushort* y1         = (ushort*)alloc((size_t)(n+1)*32*2);  // bf16, +1 sentinel zero row
    ushort* h1y        = (ushort*)alloc((size_t)(n+1)*32*2);  // bf16, +1 sentinel zero row
    ushort* h2y        = (ushort*)alloc((size_t)(n+1)*64*2);  // bf16, +1 sentinel zero row

    hipMemsetAsync(bucket_cnt, 0, zero_bytes, stream);
    // part (blocks 0..255) runs concurrently with unscaled gemm1 (blocks 256..)
    merged_kernel<<<PBLOCKS+GBLKS,1024,0,stream>>>(src, dst, bucket_cnt, recs, E, x, W1, y1);
    // CSR build (slice-sorted, sentinel-padded) + dinv + deferred y1 scale
    bucket_csr_kernel<<<NBUCK,1024,0,stream>>>(recs, bucket_cnt, csr, row_start, row_end, dinv, y1, n);
    // layer 1 propagate
    prop1_kernel<<<((n+1)*4+255)/256,256,0,stream>>>(y1, h1y, csr, row_start, row_end, dinv, b1);
    // layer 2 fused prop+GEMM
    prop_gemm_kernel<<<((n+1)*8+255)/256,256,0,stream>>>(h1y, h2y, csr, row_start, row_end, dinv, W2, b2);
    // layer 3 fused prop+pooling
    prop_pool_kernel<<<n/32,256,0,stream>>>(h2y, csr, row_start, row_end, dinv, batch, pool);
    // tiny head
    head_kernel<<<NG,128,0,stream>>>(pool, batch, n, W3, b3, Wl1, bl1, Wl2, bl2, (float*)d_out);
}